// Round 1
// baseline (331.639 us; speedup 1.0000x reference)
//
#include <hip/hip_runtime.h>
#include <hip/hip_bf16.h>

// Scaled dot-product attention (causal), B=2 H=16 S=2048 D=64, fp32 in/out.
// Flash-attention: per block 64 q-rows (4 waves x 16 rows), KV tiles of 64,
// bf16 MFMA 16x16x32, online softmax, P routed through swizzled LDS.

typedef __attribute__((ext_vector_type(8))) short bf16x8;
typedef __attribute__((ext_vector_type(4))) float f32x4;

#define MFMA16(a, b, c) __builtin_amdgcn_mfma_f32_16x16x32_bf16(a, b, c, 0, 0, 0)

constexpr int Bsz = 2, Hn = 16, Sn = 2048, Dn = 64;
constexpr int QBLK = 64, KBLK = 64, NW = 4;

__device__ inline short f2bf(float f) {
  union { float f; unsigned u; } v;
  v.f = f;
  unsigned r = v.u + 0x7FFF + ((v.u >> 16) & 1);  // RNE
  return (short)(r >> 16);
}

__global__ __launch_bounds__(256) void attn_fwd(
    const float* __restrict__ Q, const float* __restrict__ K,
    const float* __restrict__ V, const float* __restrict__ SF,
    float* __restrict__ O) {
  // per-wave 16x64 bf16 P tile, XOR-swizzled (st: byte ^= (row&7)<<4)
  __shared__ short Plds[NW * 16 * 64];

  const int qt = blockIdx.x;   // q tile 0..31
  const int bh = blockIdx.y;   // batch-head 0..31
  const int tid = threadIdx.x;
  const int wave = tid >> 6, lane = tid & 63;
  const int g = lane >> 4, lc = lane & 15;
  const float isf = 1.0f / SF[0];

  const size_t base = (size_t)bh * Sn * Dn;
  const int qrow0 = qt * QBLK + wave * 16;

  // ---- Q fragments: elem j of lane = Q[qrow0+lc][g*8 + 32*h + j] ----
  bf16x8 aq[2];
  {
    const float* qp = Q + base + (size_t)(qrow0 + lc) * Dn + g * 8;
#pragma unroll
    for (int h = 0; h < 2; ++h) {
      float4 x0 = *(const float4*)(qp + 32 * h);
      float4 x1 = *(const float4*)(qp + 32 * h + 4);
      bf16x8 a;
      a[0] = f2bf(x0.x); a[1] = f2bf(x0.y); a[2] = f2bf(x0.z); a[3] = f2bf(x0.w);
      a[4] = f2bf(x1.x); a[5] = f2bf(x1.y); a[6] = f2bf(x1.z); a[7] = f2bf(x1.w);
      aq[h] = a;
    }
  }

  f32x4 o[4];
#pragma unroll
  for (int dt = 0; dt < 4; ++dt) o[dt] = (f32x4){0.f, 0.f, 0.f, 0.f};
  float mrow[4], lrow[4];
#pragma unroll
  for (int i = 0; i < 4; ++i) { mrow[i] = -1e30f; lrow[i] = 0.f; }

  short* pw = Plds + wave * 16 * 64;

  for (int kt = 0; kt <= qt; ++kt) {   // causal tile skip
    const int kb = kt * KBLK;

    // ---- K fragments: elem j of lane = K[kb+t*16+lc][g*8 + 32*h + j] ----
    bf16x8 bk[4][2];
#pragma unroll
    for (int t = 0; t < 4; ++t) {
      const float* kp = K + base + (size_t)(kb + t * 16 + lc) * Dn + g * 8;
#pragma unroll
      for (int h = 0; h < 2; ++h) {
        float4 x0 = *(const float4*)(kp + 32 * h);
        float4 x1 = *(const float4*)(kp + 32 * h + 4);
        bf16x8 b;
        b[0] = f2bf(x0.x); b[1] = f2bf(x0.y); b[2] = f2bf(x0.z); b[3] = f2bf(x0.w);
        b[4] = f2bf(x1.x); b[5] = f2bf(x1.y); b[6] = f2bf(x1.z); b[7] = f2bf(x1.w);
        bk[t][h] = b;
      }
    }

    // ---- scores: s[t][i] = S[q = qrow0+g*4+i][k = kb+t*16+lc] ----
    f32x4 s[4];
#pragma unroll
    for (int t = 0; t < 4; ++t) {
      f32x4 z = (f32x4){0.f, 0.f, 0.f, 0.f};
      z = MFMA16(aq[0], bk[t][0], z);
      z = MFMA16(aq[1], bk[t][1], z);
      s[t] = z;
    }
    // scale + causal mask
#pragma unroll
    for (int t = 0; t < 4; ++t) {
#pragma unroll
      for (int i = 0; i < 4; ++i) {
        int qg = qrow0 + g * 4 + i;
        int kg = kb + t * 16 + lc;
        float vv = s[t][i] * isf;
        s[t][i] = (kg <= qg) ? vv : -1e30f;
      }
    }

    // ---- online softmax (wave-parallel; row spread over 16 lanes x 4 tiles) ----
    float pr[4][4];
#pragma unroll
    for (int i = 0; i < 4; ++i) {
      float tm = fmaxf(fmaxf(s[0][i], s[1][i]), fmaxf(s[2][i], s[3][i]));
#pragma unroll
      for (int msk = 1; msk < 16; msk <<= 1) tm = fmaxf(tm, __shfl_xor(tm, msk, 64));
      float mnew = fmaxf(mrow[i], tm);
      float alpha = __expf(mrow[i] - mnew);
      float rs = 0.f;
#pragma unroll
      for (int t = 0; t < 4; ++t) {
        float p = __expf(s[t][i] - mnew);
        pr[t][i] = p;
        rs += p;
      }
#pragma unroll
      for (int msk = 1; msk < 16; msk <<= 1) rs += __shfl_xor(rs, msk, 64);
      lrow[i] = lrow[i] * alpha + rs;
      mrow[i] = mnew;
#pragma unroll
      for (int dt = 0; dt < 4; ++dt) o[dt][i] *= alpha;
    }

    // ---- P -> LDS (bf16, swizzled), then read back as A-fragments ----
#pragma unroll
    for (int t = 0; t < 4; ++t) {
#pragma unroll
      for (int i = 0; i < 4; ++i) {
        int r = g * 4 + i, c = t * 16 + lc;
        int byte = (r * 128 + c * 2) ^ ((r & 7) << 4);
        *(short*)((char*)pw + byte) = f2bf(pr[t][i]);
      }
    }
    asm volatile("s_waitcnt lgkmcnt(0)" ::: "memory");
    bf16x8 pa[2];
#pragma unroll
    for (int h = 0; h < 2; ++h) {
      int byte = (lc * 128 + g * 16 + 64 * h) ^ ((lc & 7) << 4);
      pa[h] = *(const bf16x8*)((const char*)pw + byte);
    }

    // ---- V fragments (elem j = V[kb+g*8+32h+j][dt*16+lc]) + PV ----
#pragma unroll
    for (int h = 0; h < 2; ++h) {
      bf16x8 bv[4];
#pragma unroll
      for (int dt = 0; dt < 4; ++dt) {
        bf16x8 b;
#pragma unroll
        for (int j = 0; j < 8; ++j) {
          b[j] = f2bf(V[base + (size_t)(kb + g * 8 + 32 * h + j) * Dn + dt * 16 + lc]);
        }
        bv[dt] = b;
      }
#pragma unroll
      for (int dt = 0; dt < 4; ++dt) o[dt] = MFMA16(pa[h], bv[dt], o[dt]);
    }
  }

  // ---- epilogue: O[q][d] = o / l ----
#pragma unroll
  for (int i = 0; i < 4; ++i) {
    float inv = 1.0f / lrow[i];
    int qg = qrow0 + g * 4 + i;
    float* op = O + base + (size_t)qg * Dn;
#pragma unroll
    for (int dt = 0; dt < 4; ++dt) op[dt * 16 + lc] = o[dt][i] * inv;
  }
}

extern "C" void kernel_launch(void* const* d_in, const int* in_sizes, int n_in,
                              void* d_out, int out_size, void* d_ws, size_t ws_size,
                              hipStream_t stream) {
  const float* Q = (const float*)d_in[0];
  const float* K = (const float*)d_in[1];
  const float* V = (const float*)d_in[2];
  const float* SF = (const float*)d_in[3];
  // d_in[4] is the causal mask; it is tril(ones) by construction -> applied
  // analytically in-kernel (k <= q), not read.
  float* O = (float*)d_out;

  dim3 grid(Sn / QBLK, Bsz * Hn);
  attn_fwd<<<grid, 256, 0, stream>>>(Q, K, V, SF, O);
}

// Round 2
// 191.319 us; speedup vs baseline: 1.7334x; 1.7334x over previous
//
#include <hip/hip_runtime.h>
#include <hip/hip_bf16.h>

// Causal attention, B=2 H=16 S=2048 D=64, fp32 in/out.
// R2: cooperative LDS staging of K (row-major bf16) and V (transposed bf16),
// shared across 4 waves; swizzled layouts; mask only on diagonal tiles;
// balanced q-tile pairing. MFMA 16x16x32 bf16, online softmax, P via LDS.

typedef __attribute__((ext_vector_type(8))) short bf16x8;
typedef __attribute__((ext_vector_type(4))) float f32x4;

#define MFMA16(a, b, c) __builtin_amdgcn_mfma_f32_16x16x32_bf16(a, b, c, 0, 0, 0)

constexpr int Bsz = 2, Hn = 16, Sn = 2048, Dn = 64;
constexpr int QBLK = 64, KBLK = 64, NW = 4;

__device__ inline short f2bf(float f) {
  union { float f; unsigned u; } v;
  v.f = f;
  unsigned r = v.u + 0x7FFF + ((v.u >> 16) & 1);  // RNE
  return (short)(r >> 16);
}

// XOR swizzle: rows are 128B; spread same-column accesses across 16B slots.
// Mixes row&7 AND row>>4 so both fragment reads (rows vary by lc) and
// transposed V writes (rows vary by d0+j with d0 multiple of 16) spread.
__device__ inline int swz(int row, int colbyte) {
  return row * 128 + (colbyte ^ ((((row & 7) ^ ((row >> 4) << 1)) & 7) << 4));
}

__global__ __launch_bounds__(256) void attn_fwd(
    const float* __restrict__ Q, const float* __restrict__ K,
    const float* __restrict__ V, const float* __restrict__ SF,
    float* __restrict__ O) {
  __shared__ short Klds[64 * 64];           // [k][d] bf16, swizzled
  __shared__ short Vtlds[64 * 64];          // [d][k] bf16, swizzled (transposed)
  __shared__ short Plds[NW * 16 * 64];      // per-wave P tile

  const int xq = blockIdx.x;
  const int qt = (xq & 1) ? (31 - (xq >> 1)) : (xq >> 1);  // light/heavy pairing
  const int bh = blockIdx.y;
  const int tid = threadIdx.x;
  const int wave = tid >> 6, lane = tid & 63;
  const int g = lane >> 4, lc = lane & 15;
  const float isf = 1.0f / SF[0];

  const size_t base = (size_t)bh * Sn * Dn;
  const int qrow0 = qt * QBLK + wave * 16;

  // ---- Q fragments, pre-scaled by 1/sf: elem j = Q[qrow0+lc][g*8+32h+j]*isf
  bf16x8 aq[2];
  {
    const float* qp = Q + base + (size_t)(qrow0 + lc) * Dn + g * 8;
#pragma unroll
    for (int h = 0; h < 2; ++h) {
      float4 x0 = *(const float4*)(qp + 32 * h);
      float4 x1 = *(const float4*)(qp + 32 * h + 4);
      bf16x8 a;
      a[0] = f2bf(x0.x * isf); a[1] = f2bf(x0.y * isf);
      a[2] = f2bf(x0.z * isf); a[3] = f2bf(x0.w * isf);
      a[4] = f2bf(x1.x * isf); a[5] = f2bf(x1.y * isf);
      a[6] = f2bf(x1.z * isf); a[7] = f2bf(x1.w * isf);
      aq[h] = a;
    }
  }

  f32x4 o[4];
#pragma unroll
  for (int dt = 0; dt < 4; ++dt) o[dt] = (f32x4){0.f, 0.f, 0.f, 0.f};
  float mrow[4], lrow[4];
#pragma unroll
  for (int i = 0; i < 4; ++i) { mrow[i] = -1e30f; lrow[i] = 0.f; }

  short* pw = Plds + wave * 16 * 64;

  // staging assignment: thread -> 16 consecutive floats of one tile row
  const int srow = tid >> 2;            // 0..63
  const int scol = (tid & 3) * 16;      // element index 0/16/32/48

  for (int kt = 0; kt <= qt; ++kt) {
    const int kb = kt * KBLK;

    __syncthreads();  // previous tile fully consumed before overwrite

    // ---- stage K tile: coalesced fp32 loads -> bf16 LDS (row-major) ----
    {
      const float* kp = K + base + (size_t)(kb + srow) * Dn + scol;
      float4 x0 = *(const float4*)(kp + 0);
      float4 x1 = *(const float4*)(kp + 4);
      float4 x2 = *(const float4*)(kp + 8);
      float4 x3 = *(const float4*)(kp + 12);
      bf16x8 b0, b1;
      b0[0] = f2bf(x0.x); b0[1] = f2bf(x0.y); b0[2] = f2bf(x0.z); b0[3] = f2bf(x0.w);
      b0[4] = f2bf(x1.x); b0[5] = f2bf(x1.y); b0[6] = f2bf(x1.z); b0[7] = f2bf(x1.w);
      b1[0] = f2bf(x2.x); b1[1] = f2bf(x2.y); b1[2] = f2bf(x2.z); b1[3] = f2bf(x2.w);
      b1[4] = f2bf(x3.x); b1[5] = f2bf(x3.y); b1[6] = f2bf(x3.z); b1[7] = f2bf(x3.w);
      *(bf16x8*)((char*)Klds + swz(srow, scol * 2)) = b0;
      *(bf16x8*)((char*)Klds + swz(srow, scol * 2 + 16)) = b1;
    }
    // ---- stage V tile transposed: Vt[d][k] <- V[k][d] ----
    {
      const float* vp = V + base + (size_t)(kb + srow) * Dn + scol;
      float yv[16];
      *(float4*)(yv + 0) = *(const float4*)(vp + 0);
      *(float4*)(yv + 4) = *(const float4*)(vp + 4);
      *(float4*)(yv + 8) = *(const float4*)(vp + 8);
      *(float4*)(yv + 12) = *(const float4*)(vp + 12);
#pragma unroll
      for (int j = 0; j < 16; ++j) {
        *(short*)((char*)Vtlds + swz(scol + j, srow * 2)) = f2bf(yv[j]);
      }
    }
    __syncthreads();

    // ---- QK^T: s[t][i] = S[q=qrow0+g*4+i][k=kb+t*16+lc] ----
    f32x4 s[4];
#pragma unroll
    for (int t = 0; t < 4; ++t) {
      bf16x8 bk0 = *(const bf16x8*)((const char*)Klds + swz(t * 16 + lc, g * 16));
      bf16x8 bk1 = *(const bf16x8*)((const char*)Klds + swz(t * 16 + lc, g * 16 + 64));
      f32x4 z = (f32x4){0.f, 0.f, 0.f, 0.f};
      z = MFMA16(aq[0], bk0, z);
      z = MFMA16(aq[1], bk1, z);
      s[t] = z;
    }

    // causal mask: only the diagonal tile can mask
    if (kt == qt) {
#pragma unroll
      for (int t = 0; t < 4; ++t) {
#pragma unroll
        for (int i = 0; i < 4; ++i) {
          int qg = qrow0 + g * 4 + i;
          int kg = kb + t * 16 + lc;
          if (kg > qg) s[t][i] = -1e30f;
        }
      }
    }

    // ---- online softmax (row spread over 16 lanes x 4 t-tiles) ----
    float pr[4][4];
#pragma unroll
    for (int i = 0; i < 4; ++i) {
      float tm = fmaxf(fmaxf(s[0][i], s[1][i]), fmaxf(s[2][i], s[3][i]));
#pragma unroll
      for (int msk = 1; msk < 16; msk <<= 1) tm = fmaxf(tm, __shfl_xor(tm, msk, 64));
      float mnew = fmaxf(mrow[i], tm);
      float alpha = __expf(mrow[i] - mnew);
      float rs = 0.f;
#pragma unroll
      for (int t = 0; t < 4; ++t) {
        float p = __expf(s[t][i] - mnew);
        pr[t][i] = p;
        rs += p;
      }
#pragma unroll
      for (int msk = 1; msk < 16; msk <<= 1) rs += __shfl_xor(rs, msk, 64);
      lrow[i] = lrow[i] * alpha + rs;
      mrow[i] = mnew;
#pragma unroll
      for (int dt = 0; dt < 4; ++dt) o[dt][i] *= alpha;
    }

    // ---- P -> LDS (bf16), read back as A-fragments ----
#pragma unroll
    for (int t = 0; t < 4; ++t) {
#pragma unroll
      for (int i = 0; i < 4; ++i) {
        int r = g * 4 + i, c = t * 16 + lc;
        int byte = (r * 128 + c * 2) ^ ((r & 7) << 4);
        *(short*)((char*)pw + byte) = f2bf(pr[t][i]);
      }
    }
    asm volatile("s_waitcnt lgkmcnt(0)" ::: "memory");
    bf16x8 pa[2];
#pragma unroll
    for (int h = 0; h < 2; ++h) {
      int byte = (lc * 128 + g * 16 + 64 * h) ^ ((lc & 7) << 4);
      pa[h] = *(const bf16x8*)((const char*)pw + byte);
    }

    // ---- PV: bv elem j = V[kb+g*8+32h+j][dt*16+lc] = Vt[dt*16+lc][g*8+32h+j]
#pragma unroll
    for (int h = 0; h < 2; ++h) {
#pragma unroll
      for (int dt = 0; dt < 4; ++dt) {
        bf16x8 bv = *(const bf16x8*)(
            (const char*)Vtlds + swz(dt * 16 + lc, g * 16 + 64 * h));
        o[dt] = MFMA16(pa[h], bv, o[dt]);
      }
    }
  }

  // ---- epilogue: O[q][d] = o / l ----
#pragma unroll
  for (int i = 0; i < 4; ++i) {
    float inv = 1.0f / lrow[i];
    int qg = qrow0 + g * 4 + i;
    float* op = O + base + (size_t)qg * Dn;
#pragma unroll
    for (int dt = 0; dt < 4; ++dt) op[dt * 16 + lc] = o[dt][i] * inv;
  }
}

extern "C" void kernel_launch(void* const* d_in, const int* in_sizes, int n_in,
                              void* d_out, int out_size, void* d_ws, size_t ws_size,
                              hipStream_t stream) {
  const float* Q = (const float*)d_in[0];
  const float* K = (const float*)d_in[1];
  const float* V = (const float*)d_in[2];
  const float* SF = (const float*)d_in[3];
  // d_in[4] causal mask: tril by construction -> applied analytically (k<=q).
  float* O = (float*)d_out;

  dim3 grid(Sn / QBLK, Bsz * Hn);
  attn_fwd<<<grid, 256, 0, stream>>>(Q, K, V, SF, O);
}

// Round 3
// 82.447 us; speedup vs baseline: 4.0225x; 2.3205x over previous
//
#include <hip/hip_runtime.h>
#include <hip/hip_bf16.h>

// Causal attention, B=2 H=16 S=2048 D=64, fp32 in/out.
// R3: prepass converts K->bf16 and V->V^T bf16 into d_ws; main kernel stages
// tiles via global_load_lds (16B, pre-swizzled source), 2-phase double buffer,
// heavy-first dispatch. MFMA 16x16x32 bf16, online softmax, P via LDS.

typedef __attribute__((ext_vector_type(8))) short bf16x8;
typedef __attribute__((ext_vector_type(4))) float f32x4;

#define MFMA16(a, b, c) __builtin_amdgcn_mfma_f32_16x16x32_bf16(a, b, c, 0, 0, 0)

constexpr int Bsz = 2, Hn = 16, Sn = 2048, Dn = 64;
constexpr int QBLK = 64, KBLK = 64, NW = 4;
constexpr int NE = Bsz * Hn * Sn * Dn;  // 4194304 elements per tensor

__device__ inline short f2bf(float f) {
  union { float f; unsigned u; } v;
  v.f = f;
  unsigned r = v.u + 0x7FFF + ((v.u >> 16) & 1);  // RNE
  return (short)(r >> 16);
}

__device__ inline void gl2lds16(const void* g, void* l) {
  __builtin_amdgcn_global_load_lds(
      (const __attribute__((address_space(1))) unsigned int*)g,
      (__attribute__((address_space(3))) unsigned int*)l, 16, 0, 0);
}

// tile rows are 128B; XOR 16B-chunk index with row&7 -> column reads 2-way (free)
__device__ inline int swz(int row, int colbyte) {
  return row * 128 + (colbyte ^ ((row & 7) << 4));
}

// ---------------- prepass 1: fp32 -> bf16 elementwise (K) ----------------
__global__ __launch_bounds__(256) void cvt_bf16(const float* __restrict__ in,
                                                short* __restrict__ out) {
  int i = (blockIdx.x * 256 + threadIdx.x) * 8;
  const int stride = gridDim.x * 256 * 8;
  for (; i < NE; i += stride) {
    float4 a = *(const float4*)(in + i);
    float4 b = *(const float4*)(in + i + 4);
    bf16x8 r;
    r[0] = f2bf(a.x); r[1] = f2bf(a.y); r[2] = f2bf(a.z); r[3] = f2bf(a.w);
    r[4] = f2bf(b.x); r[5] = f2bf(b.y); r[6] = f2bf(b.z); r[7] = f2bf(b.w);
    *(bf16x8*)(out + i) = r;
  }
}

// ------------- prepass 2: V[bh][k][d] fp32 -> Vt[bh][d][k] bf16 -------------
__global__ __launch_bounds__(256) void transpose_v(const float* __restrict__ V,
                                                   short* __restrict__ Vt) {
  __shared__ short t[64][66];  // +2 pad -> 2-way reads (free)
  const int kt = blockIdx.x, bh = blockIdx.y;
  const int tid = threadIdx.x;
  const int r = tid >> 2, c = (tid & 3) * 16;
  const size_t base = (size_t)bh * Sn * Dn;

  const float* vp = V + base + (size_t)(kt * 64 + r) * Dn + c;
  float4 x0 = *(const float4*)(vp + 0);
  float4 x1 = *(const float4*)(vp + 4);
  float4 x2 = *(const float4*)(vp + 8);
  float4 x3 = *(const float4*)(vp + 12);
  short* tr = &t[r][c];
  tr[0] = f2bf(x0.x); tr[1] = f2bf(x0.y); tr[2] = f2bf(x0.z); tr[3] = f2bf(x0.w);
  tr[4] = f2bf(x1.x); tr[5] = f2bf(x1.y); tr[6] = f2bf(x1.z); tr[7] = f2bf(x1.w);
  tr[8] = f2bf(x2.x); tr[9] = f2bf(x2.y); tr[10] = f2bf(x2.z); tr[11] = f2bf(x2.w);
  tr[12] = f2bf(x3.x); tr[13] = f2bf(x3.y); tr[14] = f2bf(x3.z); tr[15] = f2bf(x3.w);
  __syncthreads();

  // write: thread owns output row d=r, k-slice c..c+15
  short* op = Vt + base + (size_t)r * Sn + kt * 64 + c;
  bf16x8 w0, w1;
#pragma unroll
  for (int j = 0; j < 8; ++j) { w0[j] = t[c + j][r]; w1[j] = t[c + 8 + j][r]; }
  *(bf16x8*)op = w0;
  *(bf16x8*)(op + 8) = w1;
}

// ---------------------------- main attention ----------------------------
__global__ __launch_bounds__(256) void attn_fwd(
    const float* __restrict__ Q, const short* __restrict__ Kb,
    const short* __restrict__ Vt, const float* __restrict__ SF,
    float* __restrict__ O) {
  __shared__ short Kbuf[2][64 * 64];   // [k][d] bf16, swizzled, double-buffered
  __shared__ short Vbuf[2][64 * 64];   // [d][k] bf16, swizzled, double-buffered
  __shared__ short Plds[NW * 16 * 64];

  const int bh = blockIdx.x;
  const int qt = (gridDim.y - 1) - blockIdx.y;  // heavy-first dispatch
  const int tid = threadIdx.x;
  const int wave = tid >> 6, lane = tid & 63;
  const int g = lane >> 4, lc = lane & 15;
  const float isf = 1.0f / SF[0];

  const size_t base = (size_t)bh * Sn * Dn;
  const short* Kbase = Kb + base;   // [2048][64] bf16, rows 128B contiguous
  const short* Vtbase = Vt + base;  // [64][2048] bf16, rows 4096B
  const int qrow0 = qt * QBLK + wave * 16;

  // stage one 8KB tile: wave stages chunks {2w, 2w+1} of 1KB, source pre-swizzled
  auto stageK = [&](int kt2, int buf) {
    const char* gsrc = (const char*)(Kbase + (size_t)kt2 * KBLK * Dn);
#pragma unroll
    for (int c = wave * 2; c < wave * 2 + 2; ++c) {
      int off = c * 1024 + lane * 16;
      int row = off >> 7;
      int col = (off & 127) ^ ((row & 7) << 4);
      gl2lds16(gsrc + row * 128 + col, (char*)Kbuf[buf] + c * 1024);
    }
  };
  auto stageV = [&](int kt2, int buf) {
    const char* gsrc = (const char*)(Vtbase + kt2 * KBLK);
#pragma unroll
    for (int c = wave * 2; c < wave * 2 + 2; ++c) {
      int off = c * 1024 + lane * 16;
      int row = off >> 7;  // d index
      int col = (off & 127) ^ ((row & 7) << 4);
      gl2lds16(gsrc + (size_t)row * (Sn * 2) + col, (char*)Vbuf[buf] + c * 1024);
    }
  };

  // ---- Q fragments, pre-scaled by 1/sf ----
  bf16x8 aq[2];
  {
    const float* qp = Q + base + (size_t)(qrow0 + lc) * Dn + g * 8;
#pragma unroll
    for (int h = 0; h < 2; ++h) {
      float4 x0 = *(const float4*)(qp + 32 * h);
      float4 x1 = *(const float4*)(qp + 32 * h + 4);
      bf16x8 a;
      a[0] = f2bf(x0.x * isf); a[1] = f2bf(x0.y * isf);
      a[2] = f2bf(x0.z * isf); a[3] = f2bf(x0.w * isf);
      a[4] = f2bf(x1.x * isf); a[5] = f2bf(x1.y * isf);
      a[6] = f2bf(x1.z * isf); a[7] = f2bf(x1.w * isf);
      aq[h] = a;
    }
  }

  f32x4 o[4];
#pragma unroll
  for (int dt = 0; dt < 4; ++dt) o[dt] = (f32x4){0.f, 0.f, 0.f, 0.f};
  float mrow[4], lrow[4];
#pragma unroll
  for (int i = 0; i < 4; ++i) { mrow[i] = -1e30f; lrow[i] = 0.f; }

  short* pw = Plds + wave * 16 * 64;
  const int nt = qt + 1;
  int cur = 0;

  stageK(0, 0);
  stageV(0, 0);
  __syncthreads();  // drains vmcnt -> tile 0 resident

  for (int kt = 0; kt < nt; ++kt) {
    // issue next tile's loads first (overlap with compute below)
    if (kt + 1 < nt) { stageK(kt + 1, cur ^ 1); stageV(kt + 1, cur ^ 1); }

    const char* Kc = (const char*)Kbuf[cur];
    const char* Vc = (const char*)Vbuf[cur];

    // ---- QK^T ----
    f32x4 s[4];
#pragma unroll
    for (int t = 0; t < 4; ++t) {
      bf16x8 bk0 = *(const bf16x8*)(Kc + swz(t * 16 + lc, g * 16));
      bf16x8 bk1 = *(const bf16x8*)(Kc + swz(t * 16 + lc, g * 16 + 64));
      f32x4 z = (f32x4){0.f, 0.f, 0.f, 0.f};
      z = MFMA16(aq[0], bk0, z);
      z = MFMA16(aq[1], bk1, z);
      s[t] = z;
    }

    if (kt == qt) {  // causal mask only on diagonal tile
      const int kb = kt * KBLK;
#pragma unroll
      for (int t = 0; t < 4; ++t) {
#pragma unroll
        for (int i = 0; i < 4; ++i) {
          int qg = qrow0 + g * 4 + i;
          int kg = kb + t * 16 + lc;
          if (kg > qg) s[t][i] = -1e30f;
        }
      }
    }

    // ---- online softmax ----
    float pr[4][4];
#pragma unroll
    for (int i = 0; i < 4; ++i) {
      float tm = fmaxf(fmaxf(s[0][i], s[1][i]), fmaxf(s[2][i], s[3][i]));
#pragma unroll
      for (int msk = 1; msk < 16; msk <<= 1) tm = fmaxf(tm, __shfl_xor(tm, msk, 64));
      float mnew = fmaxf(mrow[i], tm);
      float alpha = __expf(mrow[i] - mnew);
      float rs = 0.f;
#pragma unroll
      for (int t = 0; t < 4; ++t) {
        float p = __expf(s[t][i] - mnew);
        pr[t][i] = p;
        rs += p;
      }
#pragma unroll
      for (int msk = 1; msk < 16; msk <<= 1) rs += __shfl_xor(rs, msk, 64);
      lrow[i] = lrow[i] * alpha + rs;
      mrow[i] = mnew;
#pragma unroll
      for (int dt = 0; dt < 4; ++dt) o[dt][i] *= alpha;
    }

    // ---- P -> LDS (per-wave), read back as MFMA A-fragments ----
#pragma unroll
    for (int t = 0; t < 4; ++t) {
#pragma unroll
      for (int i = 0; i < 4; ++i) {
        int r = g * 4 + i, ccol = t * 16 + lc;
        int byte = (r * 128 + ccol * 2) ^ ((r & 7) << 4);
        *(short*)((char*)pw + byte) = f2bf(pr[t][i]);
      }
    }
    asm volatile("s_waitcnt lgkmcnt(0)" ::: "memory");
    bf16x8 pa[2];
#pragma unroll
    for (int h = 0; h < 2; ++h) {
      int byte = (lc * 128 + g * 16 + 64 * h) ^ ((lc & 7) << 4);
      pa[h] = *(const bf16x8*)((const char*)pw + byte);
    }

    // ---- PV ----
#pragma unroll
    for (int h = 0; h < 2; ++h) {
#pragma unroll
      for (int dt = 0; dt < 4; ++dt) {
        bf16x8 bv = *(const bf16x8*)(Vc + swz(dt * 16 + lc, g * 16 + 64 * h));
        o[dt] = MFMA16(pa[h], bv, o[dt]);
      }
    }

    __syncthreads();  // waits vmcnt (next tile landed) + all reads of cur done
    cur ^= 1;
  }

  // ---- epilogue ----
#pragma unroll
  for (int i = 0; i < 4; ++i) {
    float inv = 1.0f / lrow[i];
    int qg = qrow0 + g * 4 + i;
    float* op = O + base + (size_t)qg * Dn;
#pragma unroll
    for (int dt = 0; dt < 4; ++dt) op[dt * 16 + lc] = o[dt][i] * inv;
  }
}

extern "C" void kernel_launch(void* const* d_in, const int* in_sizes, int n_in,
                              void* d_out, int out_size, void* d_ws, size_t ws_size,
                              hipStream_t stream) {
  const float* Q = (const float*)d_in[0];
  const float* K = (const float*)d_in[1];
  const float* V = (const float*)d_in[2];
  const float* SF = (const float*)d_in[3];
  // d_in[4] causal mask: tril by construction -> applied analytically (k<=q).
  float* O = (float*)d_out;

  short* Kb = (short*)d_ws;       // [B*H][2048][64] bf16
  short* Vt = Kb + NE;            // [B*H][64][2048] bf16

  cvt_bf16<<<2048, 256, 0, stream>>>(K, Kb);
  transpose_v<<<dim3(Sn / 64, Bsz * Hn), 256, 0, stream>>>(V, Vt);
  attn_fwd<<<dim3(Bsz * Hn, Sn / QBLK), 256, 0, stream>>>(Q, Kb, Vt, SF, O);
}

// Round 5
// 64.802 us; speedup vs baseline: 5.1178x; 1.2723x over previous
//
#include <hip/hip_runtime.h>
#include <hip/hip_bf16.h>

// Causal attention, B=2 H=16 S=2048 D=64, fp32 in/out.
// R5: swapped QK^T (q lane-local) -> in-register online softmax (2 shfl),
// PV ALSO via verified mfma 16x16x32 (B-operand = lane-local packed P at
// k=16t+4g+i; A-operand = V^T LDS reads at the SAME k elements -- layout
// permutation cancels, proven by R3's passing QK^T). Defer-max, exp2 domain,
// finite sentinels. Prep: K->bf16, V->V^T bf16 (f2bf, R3-verified).
// 2-phase double-buffered global_load_lds staging, heavy-first dispatch.

typedef __attribute__((ext_vector_type(8))) short bf16x8;
typedef __attribute__((ext_vector_type(4))) short bf16x4;
typedef __attribute__((ext_vector_type(4))) float f32x4;

#define MFMA32K(a, b, c) __builtin_amdgcn_mfma_f32_16x16x32_bf16(a, b, c, 0, 0, 0)

constexpr int Bsz = 2, Hn = 16, Sn = 2048, Dn = 64;
constexpr int QBLK = 64, KBLK = 64;
constexpr int NE = Bsz * Hn * Sn * Dn;

__device__ inline short f2bf(float f) {
  union { float f; unsigned u; } v;
  v.f = f;
  unsigned r = v.u + 0x7FFF + ((v.u >> 16) & 1);  // RNE
  return (short)(r >> 16);
}

__device__ inline unsigned pk_bf16(float lo, float hi) {
  unsigned r;
  asm("v_cvt_pk_bf16_f32 %0, %1, %2" : "=v"(r) : "v"(lo), "v"(hi));
  return r;
}

__device__ inline void gl2lds16(const void* g, void* l) {
  __builtin_amdgcn_global_load_lds(
      (const __attribute__((address_space(1))) unsigned int*)g,
      (__attribute__((address_space(3))) unsigned int*)l, 16, 0, 0);
}

// tile rows = 128B; XOR 16B-slot index with row&7 (involution, both sides)
__device__ inline int swz(int row, int colbyte) {
  return row * 128 + (colbyte ^ ((row & 7) << 4));
}

// ------- prepass (merged): z=0: K fp32->bf16; z=1: V -> V^T bf16 -------
__global__ __launch_bounds__(256) void prep(const float* __restrict__ K,
                                            const float* __restrict__ V,
                                            short* __restrict__ Kb,
                                            short* __restrict__ Vt) {
  const int tile = blockIdx.x, bh = blockIdx.y;
  const int tid = threadIdx.x;
  const int r = tid >> 2, c = (tid & 3) * 16;
  const size_t base = (size_t)bh * Sn * Dn;

  if (blockIdx.z == 0) {
    const float* kp = K + base + (size_t)(tile * 64 + r) * Dn + c;
    float4 x0 = *(const float4*)(kp + 0);
    float4 x1 = *(const float4*)(kp + 4);
    float4 x2 = *(const float4*)(kp + 8);
    float4 x3 = *(const float4*)(kp + 12);
    bf16x8 w0, w1;
    w0[0] = f2bf(x0.x); w0[1] = f2bf(x0.y); w0[2] = f2bf(x0.z); w0[3] = f2bf(x0.w);
    w0[4] = f2bf(x1.x); w0[5] = f2bf(x1.y); w0[6] = f2bf(x1.z); w0[7] = f2bf(x1.w);
    w1[0] = f2bf(x2.x); w1[1] = f2bf(x2.y); w1[2] = f2bf(x2.z); w1[3] = f2bf(x2.w);
    w1[4] = f2bf(x3.x); w1[5] = f2bf(x3.y); w1[6] = f2bf(x3.z); w1[7] = f2bf(x3.w);
    short* op = Kb + base + (size_t)(tile * 64 + r) * Dn + c;
    *(bf16x8*)op = w0;
    *(bf16x8*)(op + 8) = w1;
  } else {
    __shared__ short t[64][66];  // +2 pad
    const float* vp = V + base + (size_t)(tile * 64 + r) * Dn + c;
    float4 x0 = *(const float4*)(vp + 0);
    float4 x1 = *(const float4*)(vp + 4);
    float4 x2 = *(const float4*)(vp + 8);
    float4 x3 = *(const float4*)(vp + 12);
    short* tr = &t[r][c];
    tr[0] = f2bf(x0.x); tr[1] = f2bf(x0.y); tr[2] = f2bf(x0.z); tr[3] = f2bf(x0.w);
    tr[4] = f2bf(x1.x); tr[5] = f2bf(x1.y); tr[6] = f2bf(x1.z); tr[7] = f2bf(x1.w);
    tr[8] = f2bf(x2.x); tr[9] = f2bf(x2.y); tr[10] = f2bf(x2.z); tr[11] = f2bf(x2.w);
    tr[12] = f2bf(x3.x); tr[13] = f2bf(x3.y); tr[14] = f2bf(x3.z); tr[15] = f2bf(x3.w);
    __syncthreads();
    short* op = Vt + base + (size_t)r * Sn + tile * 64 + c;
    bf16x8 w0, w1;
#pragma unroll
    for (int j = 0; j < 8; ++j) { w0[j] = t[c + j][r]; w1[j] = t[c + 8 + j][r]; }
    *(bf16x8*)op = w0;
    *(bf16x8*)(op + 8) = w1;
  }
}

// ---------------------------- main attention ----------------------------
__global__ __launch_bounds__(256) void attn_fwd(
    const float* __restrict__ Q, const short* __restrict__ Kb,
    const short* __restrict__ Vt, const float* __restrict__ SF,
    float* __restrict__ O) {
  __shared__ short Kbuf[2][64 * 64];   // [k][d] bf16, swizzled
  __shared__ short Vbuf[2][64 * 64];   // [d][k] bf16, swizzled

  const int bh = blockIdx.x;
  const int qt = (gridDim.y - 1) - blockIdx.y;  // heavy-first
  const int tid = threadIdx.x;
  const int wave = tid >> 6, lane = tid & 63;
  const int g = lane >> 4, lc = lane & 15;
  // fold log2(e) into the QK scale -> softmax in exp2 domain
  const float qscale = 1.4426950408889634f / SF[0];

  const size_t base = (size_t)bh * Sn * Dn;
  const short* Kbase = Kb + base;
  const short* Vtbase = Vt + base;
  const int qrow0 = qt * QBLK + wave * 16;
  const int qg = qrow0 + lc;  // this lane's q row

  auto stageK = [&](int kt2, int buf) {
    const char* gsrc = (const char*)(Kbase + (size_t)kt2 * KBLK * Dn);
#pragma unroll
    for (int c = wave * 2; c < wave * 2 + 2; ++c) {
      int off = c * 1024 + lane * 16;
      int row = off >> 7;
      int col = (off & 127) ^ ((row & 7) << 4);
      gl2lds16(gsrc + row * 128 + col, (char*)Kbuf[buf] + c * 1024);
    }
  };
  auto stageV = [&](int kt2, int buf) {
    const char* gsrc = (const char*)(Vtbase + kt2 * KBLK);
#pragma unroll
    for (int c = wave * 2; c < wave * 2 + 2; ++c) {
      int off = c * 1024 + lane * 16;
      int row = off >> 7;  // d
      int col = (off & 127) ^ ((row & 7) << 4);
      gl2lds16(gsrc + (size_t)row * (Sn * 2) + col, (char*)Vbuf[buf] + c * 1024);
    }
  };

  // ---- Q fragment (B operand): elem j = Q[qg][g*8+32h+j] * qscale ----
  bf16x8 bq[2];
  {
    const float* qp = Q + base + (size_t)qg * Dn + g * 8;
#pragma unroll
    for (int h = 0; h < 2; ++h) {
      float4 x0 = *(const float4*)(qp + 32 * h);
      float4 x1 = *(const float4*)(qp + 32 * h + 4);
      bf16x8 a;
      a[0] = f2bf(x0.x * qscale); a[1] = f2bf(x0.y * qscale);
      a[2] = f2bf(x0.z * qscale); a[3] = f2bf(x0.w * qscale);
      a[4] = f2bf(x1.x * qscale); a[5] = f2bf(x1.y * qscale);
      a[6] = f2bf(x1.z * qscale); a[7] = f2bf(x1.w * qscale);
      bq[h] = a;
    }
  }

  f32x4 o[4];
#pragma unroll
  for (int dt = 0; dt < 4; ++dt) o[dt] = (f32x4){0.f, 0.f, 0.f, 0.f};
  float m = -10000.0f, l = 0.f;  // finite sentinel; first tile always rescales

  const int nt = qt + 1;
  int cur = 0;
  stageK(0, 0);
  stageV(0, 0);
  __syncthreads();

  for (int kt = 0; kt < nt; ++kt) {
    if (kt + 1 < nt) { stageK(kt + 1, cur ^ 1); stageV(kt + 1, cur ^ 1); }

    const char* Kc = (const char*)Kbuf[cur];
    const char* Vc = (const char*)Vbuf[cur];

    // ---- swapped QK^T: s[t][i] = S[q=qg][k = kb+t*16+g*4+i] ----
    f32x4 s[4];
#pragma unroll
    for (int t = 0; t < 4; ++t) {
      bf16x8 ak0 = *(const bf16x8*)(Kc + swz(t * 16 + lc, g * 16));
      bf16x8 ak1 = *(const bf16x8*)(Kc + swz(t * 16 + lc, g * 16 + 64));
      f32x4 z = (f32x4){0.f, 0.f, 0.f, 0.f};
      z = MFMA32K(ak0, bq[0], z);
      z = MFMA32K(ak1, bq[1], z);
      s[t] = z;
    }

    if (kt == qt) {  // causal mask on diagonal tile only
      const int kb = kt * KBLK;
#pragma unroll
      for (int t = 0; t < 4; ++t) {
#pragma unroll
        for (int i = 0; i < 4; ++i) {
          int kg = kb + t * 16 + g * 4 + i;
          if (kg > qg) s[t][i] = -30000.0f;
        }
      }
    }

    // ---- in-register online softmax (exp2 domain), defer-max THR=8 ----
    float pmax = fmaxf(fmaxf(s[0][0], s[0][1]), fmaxf(s[0][2], s[0][3]));
#pragma unroll
    for (int t = 1; t < 4; ++t) {
      pmax = fmaxf(pmax, fmaxf(fmaxf(s[t][0], s[t][1]), fmaxf(s[t][2], s[t][3])));
    }
    pmax = fmaxf(pmax, __shfl_xor(pmax, 16, 64));
    pmax = fmaxf(pmax, __shfl_xor(pmax, 32, 64));
    if (!__all(pmax - m <= 8.0f)) {
      float mnew = fmaxf(m, pmax);
      float alpha = exp2f(m - mnew);
      l *= alpha;
#pragma unroll
      for (int dt = 0; dt < 4; ++dt) o[dt] *= alpha;
      m = mnew;
    }
    float rs = 0.f;
#pragma unroll
    for (int t = 0; t < 4; ++t) {
#pragma unroll
      for (int i = 0; i < 4; ++i) {
        float p = exp2f(s[t][i] - m);
        s[t][i] = p;
        rs += p;
      }
    }
    rs += __shfl_xor(rs, 16, 64);
    rs += __shfl_xor(rs, 32, 64);
    l += rs;

    // ---- PV via mfma 16x16x32: B-regs = lane-local P (k=16t+4g+i),
    //      A-regs = V^T at the SAME k elements (permutation cancels) ----
#pragma unroll
    for (int t2 = 0; t2 < 2; ++t2) {
      union { unsigned uu[4]; bf16x8 v; } pb;
      pb.uu[0] = pk_bf16(s[2 * t2][0], s[2 * t2][1]);
      pb.uu[1] = pk_bf16(s[2 * t2][2], s[2 * t2][3]);
      pb.uu[2] = pk_bf16(s[2 * t2 + 1][0], s[2 * t2 + 1][1]);
      pb.uu[3] = pk_bf16(s[2 * t2 + 1][2], s[2 * t2 + 1][3]);
#pragma unroll
      for (int dt = 0; dt < 4; ++dt) {
        union { bf16x4 h[2]; bf16x8 v; } av;
        av.h[0] = *(const bf16x4*)(Vc + swz(dt * 16 + lc, t2 * 64 + g * 8));
        av.h[1] = *(const bf16x4*)(Vc + swz(dt * 16 + lc, t2 * 64 + 32 + g * 8));
        o[dt] = MFMA32K(av.v, pb.v, o[dt]);
      }
    }

    __syncthreads();  // next tile landed (vmcnt) + cur fully consumed
    cur ^= 1;
  }

  // ---- epilogue: O[q][d] = o / l, coalesced f32x4 stores ----
  const float inv = 1.0f / l;
  float* op = O + base + (size_t)qg * Dn;
#pragma unroll
  for (int dt = 0; dt < 4; ++dt) {
    f32x4 r = o[dt] * inv;
    *(f32x4*)(op + dt * 16 + g * 4) = r;
  }
}

extern "C" void kernel_launch(void* const* d_in, const int* in_sizes, int n_in,
                              void* d_out, int out_size, void* d_ws, size_t ws_size,
                              hipStream_t stream) {
  const float* Q = (const float*)d_in[0];
  const float* K = (const float*)d_in[1];
  const float* V = (const float*)d_in[2];
  const float* SF = (const float*)d_in[3];
  // d_in[4] causal mask: tril by construction -> applied analytically (k<=q).
  float* O = (float*)d_out;

  short* Kb = (short*)d_ws;  // [B*H][2048][64] bf16
  short* Vt = Kb + NE;       // [B*H][64][2048] bf16

  prep<<<dim3(Sn / 64, Bsz * Hn, 2), 256, 0, stream>>>(K, V, Kb, Vt);
  attn_fwd<<<dim3(Bsz * Hn, Sn / QBLK), 256, 0, stream>>>(Q, Kb, Vt, SF, O);
}